// Round 11
// baseline (55.257 us; speedup 1.0000x reference)
//
#include <hip/hip_runtime.h>

typedef unsigned int uint32;
typedef unsigned short ushort16;
typedef __attribute__((ext_vector_type(4)))  float f32x4;
typedef __attribute__((ext_vector_type(16))) float f32x16;
typedef __attribute__((ext_vector_type(8)))  short short8;

#define THREADS 256
#define FR 4        // 32-row A-fragments per wave -> 128 queries/wave
#define QB 512      // queries per block (4 waves)
#define CH 16       // 32-point tiles per LDS chunk (16 * 1 KB = 16 KB/buf)
#define JS 8        // j-slices
#define RB 128      // reduce stage-1 blocks

__device__ inline ushort16 bf16rn(float x) {
    uint32 u = __float_as_uint(x);
    u += 0x7FFFu + ((u >> 16) & 1u);
    return (ushort16)(u >> 16);
}
__device__ inline float bf2f(ushort16 h) { return __uint_as_float(((uint32)h) << 16); }

// K=16 slot map. Per coord c (4 slots): q:[h,h,m,m]  s:[bh,bm,bh,bm] where
// b=-2c -> dot contributes (h+m)(bh+bm) = -2*c_q*c_s + O(2^-17).
// Slots 12..14: q:[1,1,1], s: 3-level split of |p|^2. Slot 15: 0.
// Padded scan points: s12 = bf16(1e30) sentinel.
__device__ inline void prep_one(const float* __restrict__ P, int np, int i,
                                short8* __restrict__ Qf, short8* __restrict__ Sf,
                                float* __restrict__ a2)
{
    ushort16 qs[16], ss[16];
#pragma unroll
    for (int s = 0; s < 16; ++s) { qs[s] = 0; ss[s] = 0; }
    float w = 0.f;
    if (i < np) {
        float c[3] = {P[3*i], P[3*i+1], P[3*i+2]};
        w = fmaf(c[0], c[0], fmaf(c[1], c[1], c[2]*c[2]));
#pragma unroll
        for (int cc = 0; cc < 3; ++cc) {
            ushort16 h = bf16rn(c[cc]);
            ushort16 m = bf16rn(c[cc] - bf2f(h));
            float bv = -2.f * c[cc];
            ushort16 bh = bf16rn(bv);
            ushort16 bm = bf16rn(bv - bf2f(bh));
            const int b = 4*cc;
            qs[b]=h;  qs[b+1]=h;  qs[b+2]=m;  qs[b+3]=m;
            ss[b]=bh; ss[b+1]=bm; ss[b+2]=bh; ss[b+3]=bm;
        }
        qs[12]=0x3F80; qs[13]=0x3F80; qs[14]=0x3F80;
        ushort16 wh = bf16rn(w);
        float r1 = w - bf2f(wh);
        ushort16 wm = bf16rn(r1);
        ushort16 wl = bf16rn(r1 - bf2f(wm));
        ss[12]=wh; ss[13]=wm; ss[14]=wl;
    } else {
        ss[12] = bf16rn(1e30f);
    }
    a2[i] = w;
    const int row = i & 31, grp = i >> 5;
#pragma unroll
    for (int h = 0; h < 2; ++h) {
        short8 qv, sv;
#pragma unroll
        for (int e = 0; e < 8; ++e) { qv[e] = (short)qs[8*h+e]; sv[e] = (short)ss[8*h+e]; }
        Qf[(size_t)grp*64 + h*32 + row] = qv;
        Sf[(size_t)grp*64 + h*32 + row] = sv;
    }
}

__global__ __launch_bounds__(THREADS) void cd_prep(
    const float* __restrict__ A, int n, int padN,
    const float* __restrict__ B, int m, int padM,
    short8* QfA, short8* SfA, float* a2A,
    short8* QfB, short8* SfB, float* a2B,
    uint32* bits)
{
    const int i = blockIdx.x * THREADS + threadIdx.x;
    if (i < n + m) bits[i] = 0x7F800000u;  // +inf
    if (i < padN) prep_one(A, n, i, QfA, SfA, a2A);
    if (i < padM) prep_one(B, m, i, QfB, SfB, a2B);
}

// 32x32x16 MFMA chamfer pass, both directions (blockIdx.z). Wave: 128 queries
// as 4 A-frags (loaded once); streams 32-point B-frag tiles from LDS (1
// ds_read_b128/lane/tile -> 4 MFMA), folds 2 tiles at a time with v_min3.
// C layout (m74/m101): col=lane&31, row=(reg&3)+8*(reg>>2)+4*(lane>>5).
// Min over 32 cols = 5-step shfl_xor butterfly; a2 added at tail; atomicMin
// on float bits (order-independent => deterministic).
__global__ __launch_bounds__(THREADS, 2) void cd_mfma(
    const short8* __restrict__ QfA, const short8* __restrict__ SfA,
    const float* __restrict__ a2A, int padN, int n,
    const short8* __restrict__ QfB, const short8* __restrict__ SfB,
    const float* __restrict__ a2B, int padM, int m,
    uint32* __restrict__ bits)
{
    __shared__ short8 sb[2][CH*64];

    const short8* Qf; const short8* Sf; const float* a2; uint32* outb;
    int nq, padQ, padS;
    if (blockIdx.z == 0) { Qf=QfA; a2=a2A; nq=n; padQ=padN; Sf=SfB; padS=padM; outb=bits;   }
    else                 { Qf=QfB; a2=a2B; nq=m; padQ=padM; Sf=SfA; padS=padN; outb=bits+n; }

    if ((int)(blockIdx.x * QB) >= padQ) return;
    const int ntiles = padS >> 5;
    const int tps = ((ntiles + JS*CH - 1) / (JS*CH)) * CH;
    const int t0 = blockIdx.y * tps;
    const int t1 = min(t0 + tps, ntiles);
    if (t0 >= t1) return;

    const int tid = threadIdx.x, lane = tid & 63, wid = tid >> 6;
    const int qbase = blockIdx.x * QB + wid * (FR * 32);

    short8 av[FR];
#pragma unroll
    for (int f = 0; f < FR; ++f)
        av[f] = Qf[(size_t)((qbase >> 5) + f) * 64 + lane];

    float rmin[FR][16];
#pragma unroll
    for (int f = 0; f < FR; ++f)
#pragma unroll
        for (int r = 0; r < 16; ++r) rmin[f][r] = 1e30f;

    const f32x16 zero = {0.f,0.f,0.f,0.f,0.f,0.f,0.f,0.f,
                         0.f,0.f,0.f,0.f,0.f,0.f,0.f,0.f};
    const int nch = (t1 - t0 + CH - 1) / CH;

    // prologue: stage chunk 0
    {
        const int elems = min(CH, t1 - t0) * 64;
#pragma unroll
        for (int r = 0; r < 4; ++r) {
            const int idx = r*256 + tid;
            if (idx < elems) sb[0][idx] = Sf[(size_t)t0*64 + idx];
        }
    }
    __syncthreads();

    int cur = 0;
    for (int ch = 0; ch < nch; ++ch) {
        const int tb = t0 + ch*CH;
        const int cnt = min(CH, t1 - tb);

        // issue next chunk's global loads EARLY
        short8 st0, st1, st2, st3;
        bool sv0=false, sv1=false, sv2=false, sv3=false;
        if (ch + 1 < nch) {
            const int nb = tb + CH;
            const int nel = min(CH, t1 - nb) * 64;
            const size_t gb = (size_t)nb * 64;
            if (tid       < nel) { st0 = Sf[gb + tid      ]; sv0 = true; }
            if (tid + 256 < nel) { st1 = Sf[gb + tid + 256]; sv1 = true; }
            if (tid + 512 < nel) { st2 = Sf[gb + tid + 512]; sv2 = true; }
            if (tid + 768 < nel) { st3 = Sf[gb + tid + 768]; sv3 = true; }
        }

        int t = 0;
        for (; t + 2 <= cnt; t += 2) {
            const short8 b0 = sb[cur][t*64 + lane];
            const short8 b1 = sb[cur][t*64 + 64 + lane];
#pragma unroll
            for (int f = 0; f < FR; ++f) {
                const f32x16 c0 = __builtin_amdgcn_mfma_f32_32x32x16_bf16(av[f], b0, zero, 0, 0, 0);
                const f32x16 c1 = __builtin_amdgcn_mfma_f32_32x32x16_bf16(av[f], b1, zero, 0, 0, 0);
#pragma unroll
                for (int r = 0; r < 16; ++r)
                    rmin[f][r] = fminf(fminf(rmin[f][r], c0[r]), c1[r]);  // v_min3
            }
        }
        if (t < cnt) {
            const short8 b0 = sb[cur][t*64 + lane];
#pragma unroll
            for (int f = 0; f < FR; ++f) {
                const f32x16 c = __builtin_amdgcn_mfma_f32_32x32x16_bf16(av[f], b0, zero, 0, 0, 0);
#pragma unroll
                for (int r = 0; r < 16; ++r) rmin[f][r] = fminf(rmin[f][r], c[r]);
            }
        }

        if (ch + 1 < nch) {  // write-late into the other buffer
            if (sv0) sb[cur^1][tid      ] = st0;
            if (sv1) sb[cur^1][tid + 256] = st1;
            if (sv2) sb[cur^1][tid + 512] = st2;
            if (sv3) sb[cur^1][tid + 768] = st3;
        }
        __syncthreads();
        cur ^= 1;
    }

    // min over the 32 columns: butterfly within each 32-lane half
#pragma unroll
    for (int f = 0; f < FR; ++f)
#pragma unroll
        for (int r = 0; r < 16; ++r) {
            float v = rmin[f][r];
            v = fminf(v, __shfl_xor(v, 1, 64));
            v = fminf(v, __shfl_xor(v, 2, 64));
            v = fminf(v, __shfl_xor(v, 4, 64));
            v = fminf(v, __shfl_xor(v, 8, 64));
            v = fminf(v, __shfl_xor(v, 16, 64));
            rmin[f][r] = v;
        }
    if ((lane & 31) == 0) {
        const int h4 = (lane >> 5) * 4;
#pragma unroll
        for (int f = 0; f < FR; ++f)
#pragma unroll
            for (int qq = 0; qq < 4; ++qq) {
                const int rowb = qbase + f*32 + 8*qq + h4;
                const float4 aa = *(const float4*)(a2 + rowb);
                const float av4[4] = {aa.x, aa.y, aa.z, aa.w};
#pragma unroll
                for (int e = 0; e < 4; ++e) {
                    const int qi = rowb + e;
                    if (qi < nq) {
                        const float sq = fmaxf(rmin[f][4*qq + e] + av4[e], 0.f);
                        atomicMin(&outb[qi], __float_as_uint(sq));
                    }
                }
            }
    }
}

__global__ __launch_bounds__(THREADS) void cd_reduce1(
    const uint32* __restrict__ bits, int count, double* __restrict__ partials)
{
    double s = 0.0;
    for (int i = blockIdx.x * THREADS + threadIdx.x; i < count; i += gridDim.x * THREADS)
        s += (double)sqrtf(__uint_as_float(bits[i]));
#pragma unroll
    for (int off = 32; off; off >>= 1) s += __shfl_down(s, off, 64);
    __shared__ double sw[4];
    const int lane = threadIdx.x & 63, wid = threadIdx.x >> 6;
    if (lane == 0) sw[wid] = s;
    __syncthreads();
    if (threadIdx.x == 0) partials[blockIdx.x] = sw[0] + sw[1] + sw[2] + sw[3];
}

__global__ __launch_bounds__(THREADS) void cd_reduce2(
    const double* __restrict__ partials, int nb, int total, float* __restrict__ out)
{
    double s = 0.0;
    for (int i = threadIdx.x; i < nb; i += THREADS) s += partials[i];
#pragma unroll
    for (int off = 32; off; off >>= 1) s += __shfl_down(s, off, 64);
    __shared__ double sw[4];
    const int lane = threadIdx.x & 63, wid = threadIdx.x >> 6;
    if (lane == 0) sw[wid] = s;
    __syncthreads();
    if (threadIdx.x == 0)
        out[0] = (float)((sw[0] + sw[1] + sw[2] + sw[3]) / (double)total);
}

extern "C" void kernel_launch(void* const* d_in, const int* in_sizes, int n_in,
                              void* d_out, int out_size, void* d_ws, size_t ws_size,
                              hipStream_t stream) {
    const float* a = (const float*)d_in[0];
    const float* b = (const float*)d_in[1];
    const int n = in_sizes[0] / 3;
    const int m = in_sizes[1] / 3;
    const int total = n + m;
    float* out = (float*)d_out;

    const int padN = (n + QB - 1) / QB * QB;
    const int padM = (m + QB - 1) / QB * QB;

    // ws: QfA | SfA | a2A | QfB | SfB | a2B | bits | partials
    char* wp = (char*)d_ws;
    short8* QfA = (short8*)wp;   wp += (size_t)padN * 64;
    short8* SfA = (short8*)wp;   wp += (size_t)padN * 64;
    float*  a2A = (float*)wp;    wp += (size_t)padN * 4;
    short8* QfB = (short8*)wp;   wp += (size_t)padM * 64;
    short8* SfB = (short8*)wp;   wp += (size_t)padM * 64;
    float*  a2B = (float*)wp;    wp += (size_t)padM * 4;
    uint32* bits = (uint32*)wp;  wp += (size_t)total * 4;
    wp = (char*)(((size_t)wp + 255) & ~(size_t)255);
    double* partials = (double*)wp;

    const int prepElems = max(max(padN, padM), total);
    cd_prep<<<(prepElems + THREADS - 1) / THREADS, THREADS, 0, stream>>>(
        a, n, padN, b, m, padM, QfA, SfA, a2A, QfB, SfB, a2B, bits);

    const int gx = max(padN, padM) / QB;
    dim3 grid(gx, JS, 2);
    cd_mfma<<<grid, THREADS, 0, stream>>>(QfA, SfA, a2A, padN, n,
                                          QfB, SfB, a2B, padM, m, bits);

    cd_reduce1<<<RB, THREADS, 0, stream>>>(bits, total, partials);
    cd_reduce2<<<1, THREADS, 0, stream>>>(partials, RB, total, out);
}

// Round 12
// 43.933 us; speedup vs baseline: 1.2578x; 1.2578x over previous
//
#include <hip/hip_runtime.h>

typedef unsigned int uint32;
typedef unsigned short ushort16;
typedef __attribute__((ext_vector_type(4)))  float f32x4;
typedef __attribute__((ext_vector_type(16))) float f32x16;
typedef __attribute__((ext_vector_type(8)))  short short8;

#define THREADS 256
#define FR 2        // 32-row A-fragments per wave -> 64 queries/wave
#define QB 256      // queries per block (4 waves)
#define CH 8        // 32-point tiles per LDS chunk (8 * 1 KB = 8 KB/buf)
#define JS 8        // j-slices
#define RB 128      // reduce stage-1 blocks

__device__ inline ushort16 bf16rn(float x) {
    uint32 u = __float_as_uint(x);
    u += 0x7FFFu + ((u >> 16) & 1u);
    return (ushort16)(u >> 16);
}
__device__ inline float bf2f(ushort16 h) { return __uint_as_float(((uint32)h) << 16); }

// K=16 slot map. Per coord c (4 slots): q:[h,h,m,m]  s:[bh,bm,bh,bm] where
// b=-2c -> dot contributes (h+m)(bh+bm) = -2*c_q*c_s + O(2^-17).
// Slots 12..14: q:[1,1,1], s: 3-level split of |p|^2. Slot 15: 0.
// Padded scan points: s12 = bf16(1e30) sentinel.
__device__ inline void prep_one(const float* __restrict__ P, int np, int i,
                                short8* __restrict__ Qf, short8* __restrict__ Sf,
                                float* __restrict__ a2)
{
    ushort16 qs[16], ss[16];
#pragma unroll
    for (int s = 0; s < 16; ++s) { qs[s] = 0; ss[s] = 0; }
    float w = 0.f;
    if (i < np) {
        float c[3] = {P[3*i], P[3*i+1], P[3*i+2]};
        w = fmaf(c[0], c[0], fmaf(c[1], c[1], c[2]*c[2]));
#pragma unroll
        for (int cc = 0; cc < 3; ++cc) {
            ushort16 h = bf16rn(c[cc]);
            ushort16 m = bf16rn(c[cc] - bf2f(h));
            float bv = -2.f * c[cc];
            ushort16 bh = bf16rn(bv);
            ushort16 bm = bf16rn(bv - bf2f(bh));
            const int b = 4*cc;
            qs[b]=h;  qs[b+1]=h;  qs[b+2]=m;  qs[b+3]=m;
            ss[b]=bh; ss[b+1]=bm; ss[b+2]=bh; ss[b+3]=bm;
        }
        qs[12]=0x3F80; qs[13]=0x3F80; qs[14]=0x3F80;
        ushort16 wh = bf16rn(w);
        float r1 = w - bf2f(wh);
        ushort16 wm = bf16rn(r1);
        ushort16 wl = bf16rn(r1 - bf2f(wm));
        ss[12]=wh; ss[13]=wm; ss[14]=wl;
    } else {
        ss[12] = bf16rn(1e30f);
    }
    a2[i] = w;
    const int row = i & 31, grp = i >> 5;
#pragma unroll
    for (int h = 0; h < 2; ++h) {
        short8 qv, sv;
#pragma unroll
        for (int e = 0; e < 8; ++e) { qv[e] = (short)qs[8*h+e]; sv[e] = (short)ss[8*h+e]; }
        Qf[(size_t)grp*64 + h*32 + row] = qv;
        Sf[(size_t)grp*64 + h*32 + row] = sv;
    }
}

__global__ __launch_bounds__(THREADS) void cd_prep(
    const float* __restrict__ A, int n, int padN,
    const float* __restrict__ B, int m, int padM,
    short8* QfA, short8* SfA, float* a2A,
    short8* QfB, short8* SfB, float* a2B,
    uint32* bits)
{
    const int i = blockIdx.x * THREADS + threadIdx.x;
    if (i < n + m) bits[i] = 0x7F800000u;  // +inf
    if (i < padN) prep_one(A, n, i, QfA, SfA, a2A);
    if (i < padM) prep_one(B, m, i, QfB, SfB, a2B);
}

// 32x32x16 MFMA chamfer pass, both directions (blockIdx.z). TLP-first config:
// FR=2 (64 queries/wave), 1024 blocks = 4 blocks/CU = 16 waves/CU so MFMA and
// LDS latency hide across waves. Streams 32-point B-frag tiles from LDS, 2
// MFMA per tile, folds 2 tiles at a time with v_min3 (8 min3/MFMA = optimal).
// C layout (m74/m101): col=lane&31, row=(reg&3)+8*(reg>>2)+4*(lane>>5).
// Min over 32 cols = 5-step shfl_xor butterfly; a2 added at tail; atomicMin
// on float bits (order-independent => deterministic).
__global__ __launch_bounds__(THREADS, 4) void cd_mfma(
    const short8* __restrict__ QfA, const short8* __restrict__ SfA,
    const float* __restrict__ a2A, int padN, int n,
    const short8* __restrict__ QfB, const short8* __restrict__ SfB,
    const float* __restrict__ a2B, int padM, int m,
    uint32* __restrict__ bits)
{
    __shared__ short8 sb[2][CH*64];

    const short8* Qf; const short8* Sf; const float* a2; uint32* outb;
    int nq, padQ, padS;
    if (blockIdx.z == 0) { Qf=QfA; a2=a2A; nq=n; padQ=padN; Sf=SfB; padS=padM; outb=bits;   }
    else                 { Qf=QfB; a2=a2B; nq=m; padQ=padM; Sf=SfA; padS=padN; outb=bits+n; }

    if ((int)(blockIdx.x * QB) >= padQ) return;
    const int ntiles = padS >> 5;
    const int tps = ((ntiles + JS*CH - 1) / (JS*CH)) * CH;
    const int t0 = blockIdx.y * tps;
    const int t1 = min(t0 + tps, ntiles);
    if (t0 >= t1) return;

    const int tid = threadIdx.x, lane = tid & 63, wid = tid >> 6;
    const int qbase = blockIdx.x * QB + wid * (FR * 32);

    short8 av[FR];
#pragma unroll
    for (int f = 0; f < FR; ++f)
        av[f] = Qf[(size_t)((qbase >> 5) + f) * 64 + lane];

    float rmin[FR][16];
#pragma unroll
    for (int f = 0; f < FR; ++f)
#pragma unroll
        for (int r = 0; r < 16; ++r) rmin[f][r] = 1e30f;

    const f32x16 zero = {0.f,0.f,0.f,0.f,0.f,0.f,0.f,0.f,
                         0.f,0.f,0.f,0.f,0.f,0.f,0.f,0.f};
    const int nch = (t1 - t0 + CH - 1) / CH;

    // prologue: stage chunk 0 (CH*64 = 512 elems, 2 per thread)
    {
        const int elems = min(CH, t1 - t0) * 64;
        if (tid       < elems) sb[0][tid      ] = Sf[(size_t)t0*64 + tid      ];
        if (tid + 256 < elems) sb[0][tid + 256] = Sf[(size_t)t0*64 + tid + 256];
    }
    __syncthreads();

    int cur = 0;
    for (int ch = 0; ch < nch; ++ch) {
        const int tb = t0 + ch*CH;
        const int cnt = min(CH, t1 - tb);

        // issue next chunk's global loads EARLY (hide under MFMA phase)
        short8 st0, st1;
        bool sv0=false, sv1=false;
        if (ch + 1 < nch) {
            const int nb = tb + CH;
            const int nel = min(CH, t1 - nb) * 64;
            const size_t gb = (size_t)nb * 64;
            if (tid       < nel) { st0 = Sf[gb + tid      ]; sv0 = true; }
            if (tid + 256 < nel) { st1 = Sf[gb + tid + 256]; sv1 = true; }
        }

        int t = 0;
        for (; t + 2 <= cnt; t += 2) {
            const short8 b0 = sb[cur][t*64 + lane];
            const short8 b1 = sb[cur][t*64 + 64 + lane];
            const f32x16 c00 = __builtin_amdgcn_mfma_f32_32x32x16_bf16(av[0], b0, zero, 0, 0, 0);
            const f32x16 c10 = __builtin_amdgcn_mfma_f32_32x32x16_bf16(av[1], b0, zero, 0, 0, 0);
            const f32x16 c01 = __builtin_amdgcn_mfma_f32_32x32x16_bf16(av[0], b1, zero, 0, 0, 0);
            const f32x16 c11 = __builtin_amdgcn_mfma_f32_32x32x16_bf16(av[1], b1, zero, 0, 0, 0);
#pragma unroll
            for (int r = 0; r < 16; ++r) {
                rmin[0][r] = fminf(fminf(rmin[0][r], c00[r]), c01[r]);  // v_min3
                rmin[1][r] = fminf(fminf(rmin[1][r], c10[r]), c11[r]);
            }
        }
        if (t < cnt) {
            const short8 b0 = sb[cur][t*64 + lane];
#pragma unroll
            for (int f = 0; f < FR; ++f) {
                const f32x16 c = __builtin_amdgcn_mfma_f32_32x32x16_bf16(av[f], b0, zero, 0, 0, 0);
#pragma unroll
                for (int r = 0; r < 16; ++r) rmin[f][r] = fminf(rmin[f][r], c[r]);
            }
        }

        if (ch + 1 < nch) {  // write-late into the other buffer
            if (sv0) sb[cur^1][tid      ] = st0;
            if (sv1) sb[cur^1][tid + 256] = st1;
        }
        __syncthreads();
        cur ^= 1;
    }

    // min over the 32 columns: butterfly within each 32-lane half
#pragma unroll
    for (int f = 0; f < FR; ++f)
#pragma unroll
        for (int r = 0; r < 16; ++r) {
            float v = rmin[f][r];
            v = fminf(v, __shfl_xor(v, 1, 64));
            v = fminf(v, __shfl_xor(v, 2, 64));
            v = fminf(v, __shfl_xor(v, 4, 64));
            v = fminf(v, __shfl_xor(v, 8, 64));
            v = fminf(v, __shfl_xor(v, 16, 64));
            rmin[f][r] = v;
        }
    if ((lane & 31) == 0) {
        const int h4 = (lane >> 5) * 4;
#pragma unroll
        for (int f = 0; f < FR; ++f)
#pragma unroll
            for (int qq = 0; qq < 4; ++qq) {
                const int rowb = qbase + f*32 + 8*qq + h4;
                const float4 aa = *(const float4*)(a2 + rowb);
                const float av4[4] = {aa.x, aa.y, aa.z, aa.w};
#pragma unroll
                for (int e = 0; e < 4; ++e) {
                    const int qi = rowb + e;
                    if (qi < nq) {
                        const float sq = fmaxf(rmin[f][4*qq + e] + av4[e], 0.f);
                        atomicMin(&outb[qi], __float_as_uint(sq));
                    }
                }
            }
    }
}

__global__ __launch_bounds__(THREADS) void cd_reduce1(
    const uint32* __restrict__ bits, int count, double* __restrict__ partials)
{
    double s = 0.0;
    for (int i = blockIdx.x * THREADS + threadIdx.x; i < count; i += gridDim.x * THREADS)
        s += (double)sqrtf(__uint_as_float(bits[i]));
#pragma unroll
    for (int off = 32; off; off >>= 1) s += __shfl_down(s, off, 64);
    __shared__ double sw[4];
    const int lane = threadIdx.x & 63, wid = threadIdx.x >> 6;
    if (lane == 0) sw[wid] = s;
    __syncthreads();
    if (threadIdx.x == 0) partials[blockIdx.x] = sw[0] + sw[1] + sw[2] + sw[3];
}

__global__ __launch_bounds__(THREADS) void cd_reduce2(
    const double* __restrict__ partials, int nb, int total, float* __restrict__ out)
{
    double s = 0.0;
    for (int i = threadIdx.x; i < nb; i += THREADS) s += partials[i];
#pragma unroll
    for (int off = 32; off; off >>= 1) s += __shfl_down(s, off, 64);
    __shared__ double sw[4];
    const int lane = threadIdx.x & 63, wid = threadIdx.x >> 6;
    if (lane == 0) sw[wid] = s;
    __syncthreads();
    if (threadIdx.x == 0)
        out[0] = (float)((sw[0] + sw[1] + sw[2] + sw[3]) / (double)total);
}

extern "C" void kernel_launch(void* const* d_in, const int* in_sizes, int n_in,
                              void* d_out, int out_size, void* d_ws, size_t ws_size,
                              hipStream_t stream) {
    const float* a = (const float*)d_in[0];
    const float* b = (const float*)d_in[1];
    const int n = in_sizes[0] / 3;
    const int m = in_sizes[1] / 3;
    const int total = n + m;
    float* out = (float*)d_out;

    const int padN = (n + QB - 1) / QB * QB;
    const int padM = (m + QB - 1) / QB * QB;

    // ws: QfA | SfA | a2A | QfB | SfB | a2B | bits | partials
    char* wp = (char*)d_ws;
    short8* QfA = (short8*)wp;   wp += (size_t)padN * 64;
    short8* SfA = (short8*)wp;   wp += (size_t)padN * 64;
    float*  a2A = (float*)wp;    wp += (size_t)padN * 4;
    short8* QfB = (short8*)wp;   wp += (size_t)padM * 64;
    short8* SfB = (short8*)wp;   wp += (size_t)padM * 64;
    float*  a2B = (float*)wp;    wp += (size_t)padM * 4;
    uint32* bits = (uint32*)wp;  wp += (size_t)total * 4;
    wp = (char*)(((size_t)wp + 255) & ~(size_t)255);
    double* partials = (double*)wp;

    const int prepElems = max(max(padN, padM), total);
    cd_prep<<<(prepElems + THREADS - 1) / THREADS, THREADS, 0, stream>>>(
        a, n, padN, b, m, padM, QfA, SfA, a2A, QfB, SfB, a2B, bits);

    const int gx = max(padN, padM) / QB;
    dim3 grid(gx, JS, 2);
    cd_mfma<<<grid, THREADS, 0, stream>>>(QfA, SfA, a2A, padN, n,
                                          QfB, SfB, a2B, padM, m, bits);

    cd_reduce1<<<RB, THREADS, 0, stream>>>(bits, total, partials);
    cd_reduce2<<<1, THREADS, 0, stream>>>(partials, RB, total, out);
}